// Round 6
// baseline (28000.787 us; speedup 1.0000x reference)
//
#include <hip/hip_runtime.h>
#include <hip/hip_bf16.h>
#include <hip/hip_fp16.h>

#define SEQ   4096
#define IDIM  2048
#define HDIM  2048
#define G4    8192
#define NBLK  256

// ---------------- numerics (v_exp2 / v_rcp based, ~1e-6 rel err) ----------------
__device__ __forceinline__ float fast_sig(float x) {
    float e = __builtin_amdgcn_exp2f(-1.4426950408889634f * x);   // exp(-x)
    return __builtin_amdgcn_rcpf(1.0f + e);
}
__device__ __forceinline__ float fast_tanh(float x) {
    float e = __builtin_amdgcn_exp2f(2.8853900817779268f * x);    // exp(2x)
    return 1.0f - 2.0f * __builtin_amdgcn_rcpf(e + 1.0f);
}
__device__ __forceinline__ unsigned short f2h(float f) {
    __half h = __float2half_rn(f);
    union { __half h; unsigned short s; } c; c.h = h; return c.s;
}
__device__ __forceinline__ float h2f(unsigned short u) {
    union { unsigned short s; __half h; } c; c.s = u; return __half2float(c.h);
}

// ---------------- phase 1: xg[s][g] = x[s,:] . Wih[g,:] + bih[g] + bhh[g] (bf16 store) ---
#define BM 128
#define BN 128
#define BK 16
#define LSTR (BM + 4)   // 132 words: rows stay 16B-aligned, write conflicts 2-way (free)

__global__ __launch_bounds__(256, 4)
void xg_gemm(const float* __restrict__ x, const float* __restrict__ Wih,
             const float* __restrict__ bih, const float* __restrict__ bhh,
             __hip_bfloat16* __restrict__ xg)
{
    __shared__ float As[BK][LSTR];   // [k][s]
    __shared__ float Bs[BK][LSTR];   // [k][g]
    const int t  = threadIdx.x;
    const int bG = blockIdx.x;            // 64 tiles over G4
    const int bS = blockIdx.y;            // 32 tiles over SEQ
    const int s0 = bS * BM, g0 = bG * BN;
    const int tx = t & 15, ty = t >> 4;   // 16x16 thread grid, 8x8 microtile
    const int lr = t >> 1, lk = (t & 1) * 8;

    float acc[8][8];
#pragma unroll
    for (int r = 0; r < 8; ++r)
#pragma unroll
        for (int c = 0; c < 8; ++c) acc[r][c] = 0.0f;

    const float* xp = x   + (size_t)(s0 + lr) * IDIM + lk;
    const float* wp = Wih + (size_t)(g0 + lr) * IDIM + lk;

    for (int k0 = 0; k0 < IDIM; k0 += BK) {
        float4 a0 = *(const float4*)(xp + k0);
        float4 a1 = *(const float4*)(xp + k0 + 4);
        float4 b0 = *(const float4*)(wp + k0);
        float4 b1 = *(const float4*)(wp + k0 + 4);
        __syncthreads();
        As[lk+0][lr] = a0.x; As[lk+1][lr] = a0.y; As[lk+2][lr] = a0.z; As[lk+3][lr] = a0.w;
        As[lk+4][lr] = a1.x; As[lk+5][lr] = a1.y; As[lk+6][lr] = a1.z; As[lk+7][lr] = a1.w;
        Bs[lk+0][lr] = b0.x; Bs[lk+1][lr] = b0.y; Bs[lk+2][lr] = b0.z; Bs[lk+3][lr] = b0.w;
        Bs[lk+4][lr] = b1.x; Bs[lk+5][lr] = b1.y; Bs[lk+6][lr] = b1.z; Bs[lk+7][lr] = b1.w;
        __syncthreads();
#pragma unroll
        for (int k = 0; k < BK; ++k) {
            float4 ra0 = *(const float4*)&As[k][ty*8];
            float4 ra1 = *(const float4*)&As[k][ty*8+4];
            float4 rb0 = *(const float4*)&Bs[k][tx*8];
            float4 rb1 = *(const float4*)&Bs[k][tx*8+4];
            float ra[8] = {ra0.x,ra0.y,ra0.z,ra0.w,ra1.x,ra1.y,ra1.z,ra1.w};
            float rb[8] = {rb0.x,rb0.y,rb0.z,rb0.w,rb1.x,rb1.y,rb1.z,rb1.w};
#pragma unroll
            for (int r = 0; r < 8; ++r)
#pragma unroll
                for (int c = 0; c < 8; ++c) acc[r][c] += ra[r] * rb[c];
        }
    }

    float bias[8];
#pragma unroll
    for (int c = 0; c < 8; ++c) {
        int g = g0 + tx*8 + c;
        bias[c] = bih[g] + bhh[g];
    }
#pragma unroll
    for (int r = 0; r < 8; ++r) {
        union { __hip_bfloat16 h[8]; uint4 u; } pk;
#pragma unroll
        for (int c = 0; c < 8; ++c) pk.h[c] = __float2bfloat16(acc[r][c] + bias[c]);
        *(uint4*)&xg[(size_t)(s0 + ty*8 + r) * G4 + g0 + tx*8] = pk.u;
    }
}

// ---------------- phase 2: persistent LSTM recurrence --------------------------
// 256 blocks x 256 threads, 1 block/CU. Block b owns h indices [8b, 8b+8).
//
// Round-6 sync: tag-then-fetch-once.
//  - producer (t0): 2x8B atomic data stores (8 fp16 h) -> s_waitcnt vmcnt(0)
//    (wave-0 only, no cache maintenance) -> 4B tag store. Tag at LLC implies
//    data at LLC (stores drained to coherence point before tag issued).
//  - detection: ONLY wave 0 polls (lane L checks 4 tags via 2x8B loads,
//    s_sleep throttle, __all exit). Waves 1-3 wait at s_barrier -> poll
//    request rate cut ~8x vs rounds 4/5, and data bytes are no longer
//    re-fetched every poll round (rounds 4/5 flooded the LLC fabric and
//    queued the very stores being awaited).
//  - fetch-once: after the barrier each thread does exactly 2x8B atomic
//    loads of its producer's unit. Freshness: loads issue after wave0's
//    completed poll (s_barrier release + in-order vmem issue per wave).
//  - parity double-buffer on data: block b republishes a parity slot only
//    two full device-steps after all consumers provably consumed it
//    (tag s published => iter s-2's fetch complete, see proof in journal).
__global__ __launch_bounds__(256, 1)
void lstm_rec(const float* __restrict__ Whh,
              const __hip_bfloat16* __restrict__ xg,
              float* __restrict__ hout,                 // [HDIM] final h (fp32)
              unsigned long long* __restrict__ hmsg,    // [2][2][NBLK] 8B units
              unsigned int* __restrict__ tags)          // [NBLK], zeroed
{
    __shared__ float hsh[HDIM];
    __shared__ float gsum[4][8];
    __shared__ float xgl[32];
    __shared__ float hloc[8];

    const int t  = threadIdx.x;
    const int b  = blockIdx.x;
    const int w  = t >> 6;
    const int L  = t & 63;
    const int rg = L >> 4;
    const int cg = L & 15;

    float4 wv[2][32];
#pragma unroll
    for (int mp = 0; mp < 2; ++mp) {
        const float* rp = Whh + (size_t)(w * HDIM + 8 * b + 2 * rg + mp) * HDIM + 4 * cg;
#pragma unroll
        for (int j = 0; j < 32; ++j) wv[mp][j] = *(const float4*)(rp + 64 * j);
    }

    float creg = 0.0f;              // cell state (meaningful for t<8 only)
    float hr[8];
#pragma unroll
    for (int k = 0; k < 8; ++k) hr[k] = 0.0f;     // h_0 = 0
    float xval = 0.0f;
    if (t < 32)
        xval = __bfloat162float(xg[(size_t)(t >> 3) * HDIM + 8 * b + (t & 7)]);  // s=0

    for (int s = 0; s < SEQ; ++s) {
        // stage h_s (from fetched registers) + xg_s (prefetched)
        float4 hv0 = { hr[0], hr[1], hr[2], hr[3] };
        float4 hv1 = { hr[4], hr[5], hr[6], hr[7] };
        *(float4*)&hsh[8 * t]     = hv0;
        *(float4*)&hsh[8 * t + 4] = hv1;
        if (t < 32) xgl[t] = xval;
        __syncthreads();                                   // A

        float a0 = 0.0f, a1 = 0.0f;
#pragma unroll
        for (int j = 0; j < 32; ++j) {
            float4 hv = *(const float4*)&hsh[4 * (cg + 16 * j)];
            a0 += wv[0][j].x * hv.x; a0 += wv[0][j].y * hv.y;
            a0 += wv[0][j].z * hv.z; a0 += wv[0][j].w * hv.w;
            a1 += wv[1][j].x * hv.x; a1 += wv[1][j].y * hv.y;
            a1 += wv[1][j].z * hv.z; a1 += wv[1][j].w * hv.w;
        }
#pragma unroll
        for (int mask = 1; mask <= 8; mask <<= 1) {        // reduce over cg (16 lanes)
            a0 += __shfl_xor(a0, mask, 64);
            a1 += __shfl_xor(a1, mask, 64);
        }
        if (cg == 0) { gsum[w][2 * rg] = a0; gsum[w][2 * rg + 1] = a1; }
        __syncthreads();                                   // B

        // gates on wave 0 (t<8); hloc handoff to t0 is same-wave in-order LDS
        if (t < 8) {
            float pi = gsum[0][t] + xgl[t];
            float pf = gsum[1][t] + xgl[8 + t];
            float pg = gsum[2][t] + xgl[16 + t];
            float po = gsum[3][t] + xgl[24 + t];
            float c  = fast_sig(pf) * creg + fast_sig(pi) * fast_tanh(pg);
            creg = c;
            float h  = fast_sig(po) * fast_tanh(c);
            hloc[t] = h;
            if (s == SEQ - 1) hout[8 * b + t] = h;
        }

        if (s + 1 < SEQ) {
            const int p = (s + 1) & 1;
            const unsigned tgt = (unsigned)(s + 1);

            // ---- publish (t0): data, drain, tag ----
            if (t == 0) {
                unsigned long long u0 = (unsigned long long)f2h(hloc[0])
                    | ((unsigned long long)f2h(hloc[1]) << 16)
                    | ((unsigned long long)f2h(hloc[2]) << 32)
                    | ((unsigned long long)f2h(hloc[3]) << 48);
                unsigned long long u1 = (unsigned long long)f2h(hloc[4])
                    | ((unsigned long long)f2h(hloc[5]) << 16)
                    | ((unsigned long long)f2h(hloc[6]) << 32)
                    | ((unsigned long long)f2h(hloc[7]) << 48);
                __hip_atomic_store(&hmsg[(size_t)(p * 2 + 0) * NBLK + b], u0,
                                   __ATOMIC_RELAXED, __HIP_MEMORY_SCOPE_AGENT);
                __hip_atomic_store(&hmsg[(size_t)(p * 2 + 1) * NBLK + b], u1,
                                   __ATOMIC_RELAXED, __HIP_MEMORY_SCOPE_AGENT);
                asm volatile("s_waitcnt vmcnt(0)" ::: "memory");  // data at LLC
                __hip_atomic_store(&tags[b], tgt,
                                   __ATOMIC_RELAXED, __HIP_MEMORY_SCOPE_AGENT);
            }

            // ---- detection: wave 0 only, tags are 4B, throttled ----
            if (t < 64) {
                const unsigned long long* t64 = (const unsigned long long*)tags;
                for (;;) {
                    unsigned long long ta = __hip_atomic_load(&t64[2 * t],
                                        __ATOMIC_RELAXED, __HIP_MEMORY_SCOPE_AGENT);
                    unsigned long long tb = __hip_atomic_load(&t64[2 * t + 1],
                                        __ATOMIC_RELAXED, __HIP_MEMORY_SCOPE_AGENT);
                    bool ok = (unsigned)(ta & 0xffffffffu) >= tgt &&
                              (unsigned)(ta >> 32)         >= tgt &&
                              (unsigned)(tb & 0xffffffffu) >= tgt &&
                              (unsigned)(tb >> 32)         >= tgt;
                    if (__all(ok)) break;
                    __builtin_amdgcn_s_sleep(1);
                }
            }
            // prefetch xg for s+1 (hidden under fetch+stage+dot)
            if (t < 32)
                xval = __bfloat162float(xg[(size_t)(s + 1) * G4 + (size_t)(t >> 3) * HDIM + 8 * b + (t & 7)]);
            __syncthreads();                               // C: poll done -> all may fetch

            // ---- fetch-once: thread t reads block t's 16B ----
            unsigned long long v0 = __hip_atomic_load(&hmsg[(size_t)(p * 2 + 0) * NBLK + t],
                                    __ATOMIC_RELAXED, __HIP_MEMORY_SCOPE_AGENT);
            unsigned long long v1 = __hip_atomic_load(&hmsg[(size_t)(p * 2 + 1) * NBLK + t],
                                    __ATOMIC_RELAXED, __HIP_MEMORY_SCOPE_AGENT);
            hr[0] = h2f((unsigned short)(v0      ));
            hr[1] = h2f((unsigned short)(v0 >> 16));
            hr[2] = h2f((unsigned short)(v0 >> 32));
            hr[3] = h2f((unsigned short)(v0 >> 48));
            hr[4] = h2f((unsigned short)(v1      ));
            hr[5] = h2f((unsigned short)(v1 >> 16));
            hr[6] = h2f((unsigned short)(v1 >> 32));
            hr[7] = h2f((unsigned short)(v1 >> 48));
        }
    }
}

// ---------------- phase 3: out[o] = h . Wfc[o,:] + bfc[o] ----------------------
__global__ __launch_bounds__(64)
void fc_kernel(const float* __restrict__ h, const float* __restrict__ Wfc,
               const float* __restrict__ bfc, float* __restrict__ out)
{
    const int o = blockIdx.x;
    const int L = threadIdx.x;
    const float* wr = Wfc + (size_t)o * HDIM;
    float s = 0.0f;
#pragma unroll
    for (int jj = 0; jj < 8; ++jj) {
        float4 wvv = *(const float4*)(wr + 4 * (L + 64 * jj));
        float4 hv  = *(const float4*)(h  + 4 * (L + 64 * jj));
        s += wvv.x * hv.x + wvv.y * hv.y + wvv.z * hv.z + wvv.w * hv.w;
    }
#pragma unroll
    for (int mask = 1; mask <= 32; mask <<= 1) s += __shfl_xor(s, mask, 64);
    if (L == 0) out[o] = s + bfc[o];
}

// ---------------- launcher -----------------------------------------------------
extern "C" void kernel_launch(void* const* d_in, const int* in_sizes, int n_in,
                              void* d_out, int out_size, void* d_ws, size_t ws_size,
                              hipStream_t stream)
{
    (void)in_sizes; (void)n_in; (void)out_size; (void)ws_size;
    const float* x   = (const float*)d_in[0];
    const float* Wih = (const float*)d_in[1];
    const float* Whh = (const float*)d_in[2];
    const float* bih = (const float*)d_in[3];
    const float* bhh = (const float*)d_in[4];
    const float* Wfc = (const float*)d_in[5];
    const float* bfc = (const float*)d_in[6];
    float* out = (float*)d_out;

    // ws: xg bf16 [SEQ][G4] (64 MiB) | hout f32 [HDIM] | tags u32 [NBLK] | hmsg u64 [2][2][NBLK]
    __hip_bfloat16* xg       = (__hip_bfloat16*)d_ws;
    char* base               = (char*)d_ws + (size_t)SEQ * G4 * sizeof(__hip_bfloat16);
    float* hout              = (float*)base;
    unsigned int* tags       = (unsigned int*)(base + HDIM * sizeof(float));
    unsigned long long* hmsg = (unsigned long long*)(base + HDIM * sizeof(float) + NBLK * sizeof(unsigned int));

    // ws is poisoned 0xAA pre-launch -> tags would read "fresh"; MUST zero them.
    (void)hipMemsetAsync(tags, 0, NBLK * sizeof(unsigned int), stream);

    dim3 g1(G4 / BN, SEQ / BM);  // (64, 32)
    hipLaunchKernelGGL(xg_gemm, g1, dim3(256), 0, stream, x, Wih, bih, bhh, xg);

    // lstm_rec needs all 256 blocks co-resident. Prefer the cooperative-launch
    // guarantee; if the API refuses, fall back to a plain launch: grid==256
    // with 1 block/CU on an idle 256-CU device is co-resident by construction.
    float* hout_arg = hout;
    unsigned long long* hmsg_arg = hmsg;
    unsigned int* tags_arg = tags;
    void* args[] = { (void*)&Whh, (void*)&xg, (void*)&hout_arg, (void*)&hmsg_arg, (void*)&tags_arg };
    hipError_t ce = hipLaunchCooperativeKernel((const void*)lstm_rec, dim3(NBLK), dim3(256),
                                               args, 0, stream);
    if (ce != hipSuccess) {
        hipLaunchKernelGGL(lstm_rec, dim3(NBLK), dim3(256), 0, stream, Whh, xg, hout, hmsg, tags);
    }

    hipLaunchKernelGGL(fc_kernel, dim3(2048), dim3(64), 0, stream, hout, Wfc, bfc, out);
}

// Round 7
// 24727.577 us; speedup vs baseline: 1.1324x; 1.1324x over previous
//
#include <hip/hip_runtime.h>
#include <hip/hip_bf16.h>
#include <hip/hip_fp16.h>

#define SEQ   4096
#define IDIM  2048
#define HDIM  2048
#define G4    8192
#define NBLK  256

// ---------------- numerics (v_exp2 / v_rcp based, ~1e-6 rel err) ----------------
__device__ __forceinline__ float fast_sig(float x) {
    float e = __builtin_amdgcn_exp2f(-1.4426950408889634f * x);   // exp(-x)
    return __builtin_amdgcn_rcpf(1.0f + e);
}
__device__ __forceinline__ float fast_tanh(float x) {
    float e = __builtin_amdgcn_exp2f(2.8853900817779268f * x);    // exp(2x)
    return 1.0f - 2.0f * __builtin_amdgcn_rcpf(e + 1.0f);
}
__device__ __forceinline__ unsigned short f2h(float f) {
    __half h = __float2half_rn(f);
    union { __half h; unsigned short s; } c; c.h = h; return c.s;
}
__device__ __forceinline__ float h2f(unsigned short u) {
    union { unsigned short s; __half h; } c; c.s = u; return __half2float(c.h);
}

// ---------------- phase 1: xg[s][g] = x[s,:] . Wih[g,:] + bih[g] + bhh[g] (bf16 store) ---
#define BM 128
#define BN 128
#define BK 16
#define LSTR (BM + 4)   // 132 words: rows stay 16B-aligned, write conflicts 2-way (free)

__global__ __launch_bounds__(256, 4)
void xg_gemm(const float* __restrict__ x, const float* __restrict__ Wih,
             const float* __restrict__ bih, const float* __restrict__ bhh,
             __hip_bfloat16* __restrict__ xg)
{
    __shared__ float As[BK][LSTR];   // [k][s]
    __shared__ float Bs[BK][LSTR];   // [k][g]
    const int t  = threadIdx.x;
    const int bG = blockIdx.x;            // 64 tiles over G4
    const int bS = blockIdx.y;            // 32 tiles over SEQ
    const int s0 = bS * BM, g0 = bG * BN;
    const int tx = t & 15, ty = t >> 4;   // 16x16 thread grid, 8x8 microtile
    const int lr = t >> 1, lk = (t & 1) * 8;

    float acc[8][8];
#pragma unroll
    for (int r = 0; r < 8; ++r)
#pragma unroll
        for (int c = 0; c < 8; ++c) acc[r][c] = 0.0f;

    const float* xp = x   + (size_t)(s0 + lr) * IDIM + lk;
    const float* wp = Wih + (size_t)(g0 + lr) * IDIM + lk;

    for (int k0 = 0; k0 < IDIM; k0 += BK) {
        float4 a0 = *(const float4*)(xp + k0);
        float4 a1 = *(const float4*)(xp + k0 + 4);
        float4 b0 = *(const float4*)(wp + k0);
        float4 b1 = *(const float4*)(wp + k0 + 4);
        __syncthreads();
        As[lk+0][lr] = a0.x; As[lk+1][lr] = a0.y; As[lk+2][lr] = a0.z; As[lk+3][lr] = a0.w;
        As[lk+4][lr] = a1.x; As[lk+5][lr] = a1.y; As[lk+6][lr] = a1.z; As[lk+7][lr] = a1.w;
        Bs[lk+0][lr] = b0.x; Bs[lk+1][lr] = b0.y; Bs[lk+2][lr] = b0.z; Bs[lk+3][lr] = b0.w;
        Bs[lk+4][lr] = b1.x; Bs[lk+5][lr] = b1.y; Bs[lk+6][lr] = b1.z; Bs[lk+7][lr] = b1.w;
        __syncthreads();
#pragma unroll
        for (int k = 0; k < BK; ++k) {
            float4 ra0 = *(const float4*)&As[k][ty*8];
            float4 ra1 = *(const float4*)&As[k][ty*8+4];
            float4 rb0 = *(const float4*)&Bs[k][tx*8];
            float4 rb1 = *(const float4*)&Bs[k][tx*8+4];
            float ra[8] = {ra0.x,ra0.y,ra0.z,ra0.w,ra1.x,ra1.y,ra1.z,ra1.w};
            float rb[8] = {rb0.x,rb0.y,rb0.z,rb0.w,rb1.x,rb1.y,rb1.z,rb1.w};
#pragma unroll
            for (int r = 0; r < 8; ++r)
#pragma unroll
                for (int c = 0; c < 8; ++c) acc[r][c] += ra[r] * rb[c];
        }
    }

    float bias[8];
#pragma unroll
    for (int c = 0; c < 8; ++c) {
        int g = g0 + tx*8 + c;
        bias[c] = bih[g] + bhh[g];
    }
#pragma unroll
    for (int r = 0; r < 8; ++r) {
        union { __hip_bfloat16 h[8]; uint4 u; } pk;
#pragma unroll
        for (int c = 0; c < 8; ++c) pk.h[c] = __float2bfloat16(acc[r][c] + bias[c]);
        *(uint4*)&xg[(size_t)(s0 + ty*8 + r) * G4 + g0 + tx*8] = pk.u;
    }
}

// ---------------- phase 2: persistent LSTM recurrence --------------------------
// 256 blocks x 256 threads, 1 block/CU. Block b owns h indices [8b, 8b+8).
// Wave w = gate w (i,f,g,o). Lane L: rg=L>>4 (2 rows), cg=L&15 (col chunks).
//
// Round-7: round-5 structure (fused self-validating 8B units {tag:16, 3x fp16},
// parity double-buffer, all-thread poll, data rides with tag - one LLC trip)
// with ONE change: publishes are atomic EXCHANGES, not stores. Rationale
// (rounds 4-6 post-mortem): plain sc0/sc1 stores appear to linger in CU/fabric
// write buffers for ~11k cycles before becoming visible to remote pollers
// (poll-traffic shaping changed FETCH 2x with zero effect on latency; marginal
// round trips cost only ~0.7us each). Atomic RMWs are executed AT the LLC
// bank - they cannot linger locally - so visibility should collapse to the
// one-way flight time.
__global__ __launch_bounds__(256, 1)
void lstm_rec(const float* __restrict__ Whh,
              const __hip_bfloat16* __restrict__ xg,
              float* __restrict__ hout,                 // [HDIM] final h (fp32)
              unsigned long long* __restrict__ msg)     // [2][3][NBLK], tags zeroed
{
    __shared__ float hsh[HDIM];
    __shared__ float gsum[4][8];
    __shared__ float xgl[32];
    __shared__ float hloc[8];

    const int t  = threadIdx.x;
    const int b  = blockIdx.x;
    const int w  = t >> 6;
    const int L  = t & 63;
    const int rg = L >> 4;
    const int cg = L & 15;

    float4 wv[2][32];
#pragma unroll
    for (int mp = 0; mp < 2; ++mp) {
        const float* rp = Whh + (size_t)(w * HDIM + 8 * b + 2 * rg + mp) * HDIM + 4 * cg;
#pragma unroll
        for (int j = 0; j < 32; ++j) wv[mp][j] = *(const float4*)(rp + 64 * j);
    }

    float creg = 0.0f;              // cell state (meaningful for t<8 only)
    float hreg[8];
#pragma unroll
    for (int k = 0; k < 8; ++k) hreg[k] = 0.0f;   // h_0 = 0
    float xval = 0.0f;
    if (t < 32)
        xval = __bfloat162float(xg[(size_t)(t >> 3) * HDIM + 8 * b + (t & 7)]);  // s=0

    for (int s = 0; s < SEQ; ++s) {
        // stage h_s (from polled registers) + xg_s (prefetched)
        float4 hv0 = { hreg[0], hreg[1], hreg[2], hreg[3] };
        float4 hv1 = { hreg[4], hreg[5], hreg[6], hreg[7] };
        *(float4*)&hsh[8 * t]     = hv0;
        *(float4*)&hsh[8 * t + 4] = hv1;
        if (t < 32) xgl[t] = xval;
        __syncthreads();                                   // #1

        float a0 = 0.0f, a1 = 0.0f;
#pragma unroll
        for (int j = 0; j < 32; ++j) {
            float4 hv = *(const float4*)&hsh[4 * (cg + 16 * j)];
            a0 += wv[0][j].x * hv.x; a0 += wv[0][j].y * hv.y;
            a0 += wv[0][j].z * hv.z; a0 += wv[0][j].w * hv.w;
            a1 += wv[1][j].x * hv.x; a1 += wv[1][j].y * hv.y;
            a1 += wv[1][j].z * hv.z; a1 += wv[1][j].w * hv.w;
        }
#pragma unroll
        for (int mask = 1; mask <= 8; mask <<= 1) {        // reduce over cg (16 lanes)
            a0 += __shfl_xor(a0, mask, 64);
            a1 += __shfl_xor(a1, mask, 64);
        }
        if (cg == 0) { gsum[w][2 * rg] = a0; gsum[w][2 * rg + 1] = a1; }
        __syncthreads();                                   // #2

        // gates: wave 0 only; hloc handoff to the packers (t<3) is same-wave,
        // in-order LDS -> no barrier #3 needed.
        if (t < 8) {
            float pi = gsum[0][t] + xgl[t];
            float pf = gsum[1][t] + xgl[8 + t];
            float pg = gsum[2][t] + xgl[16 + t];
            float po = gsum[3][t] + xgl[24 + t];
            float c  = fast_sig(pf) * creg + fast_sig(pi) * fast_tanh(pg);
            creg = c;
            float h  = fast_sig(po) * fast_tanh(c);
            hloc[t] = h;
            if (s == SEQ - 1) hout[8 * b + t] = h;
        }

        if (s + 1 < SEQ) {
            const int p = (s + 1) & 1;
            // publish 3 self-validating units via atomic SWAP (executes at the
            // LLC bank -> eager global visibility; old value discarded)
            if (t < 3) {
                float v0 = hloc[3 * t], v1 = hloc[3 * t + 1];
                float v2 = (3 * t + 2 < 8) ? hloc[3 * t + 2] : 0.0f;
                unsigned long long u = (unsigned long long)(unsigned short)(s + 1)
                    | ((unsigned long long)f2h(v0) << 16)
                    | ((unsigned long long)f2h(v1) << 32)
                    | ((unsigned long long)f2h(v2) << 48);
                (void)__hip_atomic_exchange(&msg[(size_t)(p * 3 + t) * NBLK + b], u,
                                            __ATOMIC_RELAXED, __HIP_MEMORY_SCOPE_AGENT);
            }
            // prefetch xg for s+1 (latency hidden under the poll)
            if (t < 32)
                xval = __bfloat162float(xg[(size_t)(s + 1) * G4 + (size_t)(t >> 3) * HDIM + 8 * b + (t & 7)]);
            // poll block t's 3 units; data rides with the tag
            const unsigned long long* p0 = &msg[(size_t)(p * 3 + 0) * NBLK + t];
            const unsigned long long* p1 = &msg[(size_t)(p * 3 + 1) * NBLK + t];
            const unsigned long long* p2 = &msg[(size_t)(p * 3 + 2) * NBLK + t];
            const unsigned tgt = (unsigned)(s + 1);
            unsigned long long v0, v1, v2;
            do {
                v0 = __hip_atomic_load(p0, __ATOMIC_RELAXED, __HIP_MEMORY_SCOPE_AGENT);
                v1 = __hip_atomic_load(p1, __ATOMIC_RELAXED, __HIP_MEMORY_SCOPE_AGENT);
                v2 = __hip_atomic_load(p2, __ATOMIC_RELAXED, __HIP_MEMORY_SCOPE_AGENT);
            } while ((unsigned)(v0 & 0xFFFFu) < tgt ||
                     (unsigned)(v1 & 0xFFFFu) < tgt ||
                     (unsigned)(v2 & 0xFFFFu) < tgt);
            hreg[0] = h2f((unsigned short)(v0 >> 16));
            hreg[1] = h2f((unsigned short)(v0 >> 32));
            hreg[2] = h2f((unsigned short)(v0 >> 48));
            hreg[3] = h2f((unsigned short)(v1 >> 16));
            hreg[4] = h2f((unsigned short)(v1 >> 32));
            hreg[5] = h2f((unsigned short)(v1 >> 48));
            hreg[6] = h2f((unsigned short)(v2 >> 16));
            hreg[7] = h2f((unsigned short)(v2 >> 32));
        }
    }
}

// ---------------- phase 3: out[o] = h . Wfc[o,:] + bfc[o] ----------------------
__global__ __launch_bounds__(64)
void fc_kernel(const float* __restrict__ h, const float* __restrict__ Wfc,
               const float* __restrict__ bfc, float* __restrict__ out)
{
    const int o = blockIdx.x;
    const int L = threadIdx.x;
    const float* wr = Wfc + (size_t)o * HDIM;
    float s = 0.0f;
#pragma unroll
    for (int jj = 0; jj < 8; ++jj) {
        float4 wvv = *(const float4*)(wr + 4 * (L + 64 * jj));
        float4 hv  = *(const float4*)(h  + 4 * (L + 64 * jj));
        s += wvv.x * hv.x + wvv.y * hv.y + wvv.z * hv.z + wvv.w * hv.w;
    }
#pragma unroll
    for (int mask = 1; mask <= 32; mask <<= 1) s += __shfl_xor(s, mask, 64);
    if (L == 0) out[o] = s + bfc[o];
}

// ---------------- launcher -----------------------------------------------------
extern "C" void kernel_launch(void* const* d_in, const int* in_sizes, int n_in,
                              void* d_out, int out_size, void* d_ws, size_t ws_size,
                              hipStream_t stream)
{
    (void)in_sizes; (void)n_in; (void)out_size; (void)ws_size;
    const float* x   = (const float*)d_in[0];
    const float* Wih = (const float*)d_in[1];
    const float* Whh = (const float*)d_in[2];
    const float* bih = (const float*)d_in[3];
    const float* bhh = (const float*)d_in[4];
    const float* Wfc = (const float*)d_in[5];
    const float* bfc = (const float*)d_in[6];
    float* out = (float*)d_out;

    // ws layout: xg bf16 [SEQ][G4] (64 MiB) | hout fp32 [HDIM] | msg u64 [2][3][NBLK]
    __hip_bfloat16* xg       = (__hip_bfloat16*)d_ws;
    float* hout              = (float*)((char*)d_ws + (size_t)SEQ * G4 * sizeof(__hip_bfloat16));
    unsigned long long* msg  = (unsigned long long*)(hout + HDIM);

    // ws is poisoned 0xAA before every launch -> tags would read as fresh; MUST zero.
    (void)hipMemsetAsync(msg, 0, 2 * 3 * NBLK * sizeof(unsigned long long), stream);

    dim3 g1(G4 / BN, SEQ / BM);  // (64, 32)
    hipLaunchKernelGGL(xg_gemm, g1, dim3(256), 0, stream, x, Wih, bih, bhh, xg);

    // lstm_rec needs all 256 blocks co-resident. Prefer the cooperative-launch
    // guarantee; if the API refuses, fall back to a plain launch: grid==256
    // with 1 block/CU on an idle 256-CU device is co-resident by construction.
    float* hout_arg = hout;
    unsigned long long* msg_arg = msg;
    void* args[] = { (void*)&Whh, (void*)&xg, (void*)&hout_arg, (void*)&msg_arg };
    hipError_t ce = hipLaunchCooperativeKernel((const void*)lstm_rec, dim3(NBLK), dim3(256),
                                               args, 0, stream);
    if (ce != hipSuccess) {
        hipLaunchKernelGGL(lstm_rec, dim3(NBLK), dim3(256), 0, stream, Whh, xg, hout, msg);
    }

    hipLaunchKernelGGL(fc_kernel, dim3(2048), dim3(64), 0, stream, hout, Wfc, bfc, out);
}

// Round 8
// 17643.309 us; speedup vs baseline: 1.5870x; 1.4015x over previous
//
#include <hip/hip_runtime.h>
#include <hip/hip_bf16.h>
#include <hip/hip_fp16.h>

#define SEQ   4096
#define IDIM  2048
#define HDIM  2048
#define G4    8192
#define NBLK  256
#define NREP  8      // message replicas: readers-per-line = NBLK/NREP = 32

// ---------------- numerics (v_exp2 / v_rcp based, ~1e-6 rel err) ----------------
__device__ __forceinline__ float fast_sig(float x) {
    float e = __builtin_amdgcn_exp2f(-1.4426950408889634f * x);   // exp(-x)
    return __builtin_amdgcn_rcpf(1.0f + e);
}
__device__ __forceinline__ float fast_tanh(float x) {
    float e = __builtin_amdgcn_exp2f(2.8853900817779268f * x);    // exp(2x)
    return 1.0f - 2.0f * __builtin_amdgcn_rcpf(e + 1.0f);
}
__device__ __forceinline__ unsigned short f2h(float f) {
    __half h = __float2half_rn(f);
    union { __half h; unsigned short s; } c; c.h = h; return c.s;
}
__device__ __forceinline__ float h2f(unsigned short u) {
    union { unsigned short s; __half h; } c; c.s = u; return __half2float(c.h);
}

// ---------------- phase 1: xg[s][g] = x[s,:] . Wih[g,:] + bih[g] + bhh[g] (bf16 store) ---
#define BM 128
#define BN 128
#define BK 16
#define LSTR (BM + 4)   // 132 words: rows stay 16B-aligned, write conflicts 2-way (free)

__global__ __launch_bounds__(256, 4)
void xg_gemm(const float* __restrict__ x, const float* __restrict__ Wih,
             const float* __restrict__ bih, const float* __restrict__ bhh,
             __hip_bfloat16* __restrict__ xg)
{
    __shared__ float As[BK][LSTR];   // [k][s]
    __shared__ float Bs[BK][LSTR];   // [k][g]
    const int t  = threadIdx.x;
    const int bG = blockIdx.x;            // 64 tiles over G4
    const int bS = blockIdx.y;            // 32 tiles over SEQ
    const int s0 = bS * BM, g0 = bG * BN;
    const int tx = t & 15, ty = t >> 4;   // 16x16 thread grid, 8x8 microtile
    const int lr = t >> 1, lk = (t & 1) * 8;

    float acc[8][8];
#pragma unroll
    for (int r = 0; r < 8; ++r)
#pragma unroll
        for (int c = 0; c < 8; ++c) acc[r][c] = 0.0f;

    const float* xp = x   + (size_t)(s0 + lr) * IDIM + lk;
    const float* wp = Wih + (size_t)(g0 + lr) * IDIM + lk;

    for (int k0 = 0; k0 < IDIM; k0 += BK) {
        float4 a0 = *(const float4*)(xp + k0);
        float4 a1 = *(const float4*)(xp + k0 + 4);
        float4 b0 = *(const float4*)(wp + k0);
        float4 b1 = *(const float4*)(wp + k0 + 4);
        __syncthreads();
        As[lk+0][lr] = a0.x; As[lk+1][lr] = a0.y; As[lk+2][lr] = a0.z; As[lk+3][lr] = a0.w;
        As[lk+4][lr] = a1.x; As[lk+5][lr] = a1.y; As[lk+6][lr] = a1.z; As[lk+7][lr] = a1.w;
        Bs[lk+0][lr] = b0.x; Bs[lk+1][lr] = b0.y; Bs[lk+2][lr] = b0.z; Bs[lk+3][lr] = b0.w;
        Bs[lk+4][lr] = b1.x; Bs[lk+5][lr] = b1.y; Bs[lk+6][lr] = b1.z; Bs[lk+7][lr] = b1.w;
        __syncthreads();
#pragma unroll
        for (int k = 0; k < BK; ++k) {
            float4 ra0 = *(const float4*)&As[k][ty*8];
            float4 ra1 = *(const float4*)&As[k][ty*8+4];
            float4 rb0 = *(const float4*)&Bs[k][tx*8];
            float4 rb1 = *(const float4*)&Bs[k][tx*8+4];
            float ra[8] = {ra0.x,ra0.y,ra0.z,ra0.w,ra1.x,ra1.y,ra1.z,ra1.w};
            float rb[8] = {rb0.x,rb0.y,rb0.z,rb0.w,rb1.x,rb1.y,rb1.z,rb1.w};
#pragma unroll
            for (int r = 0; r < 8; ++r)
#pragma unroll
                for (int c = 0; c < 8; ++c) acc[r][c] += ra[r] * rb[c];
        }
    }

    float bias[8];
#pragma unroll
    for (int c = 0; c < 8; ++c) {
        int g = g0 + tx*8 + c;
        bias[c] = bih[g] + bhh[g];
    }
#pragma unroll
    for (int r = 0; r < 8; ++r) {
        union { __hip_bfloat16 h[8]; uint4 u; } pk;
#pragma unroll
        for (int c = 0; c < 8; ++c) pk.h[c] = __float2bfloat16(acc[r][c] + bias[c]);
        *(uint4*)&xg[(size_t)(s0 + ty*8 + r) * G4 + g0 + tx*8] = pk.u;
    }
}

// ---------------- phase 2: persistent LSTM recurrence --------------------------
// 256 blocks x 256 threads, 1 block/CU. Block b owns h indices [8b, 8b+8).
// Wave w = gate w (i,f,g,o). Lane L: rg=L>>4 (2 rows), cg=L&15 (col chunks).
//
// Round-8: REPLICATED message array (theory v3: per-line reader serialization
// at the coherence point). r4-r7 showed poll-round time is invariant to line
// count, producer op type, and poller count-per-CU — the invariant was 256
// CUs reading each line; the MALL bank serializes same-line requests
// (~256 x ~10cy = ~2.5k cy/round) and the producer's write queues behind the
// flood. Fix: producers publish their 3 self-validating units to NREP=8
// replica sets (lanes t<24, one exchange each — still one vmem instruction in
// wave 0, 24 distinct lines in parallel banks); consumer block b polls only
// replica b&7 -> 32 readers/line instead of 256. Everything else identical
// to r7 (best: fused {tag:16, 3x fp16} units, parity double-buffer, atomic-
// exchange publish, all-thread poll, data rides with tag in one LLC trip).
__global__ __launch_bounds__(256, 1)
void lstm_rec(const float* __restrict__ Whh,
              const __hip_bfloat16* __restrict__ xg,
              float* __restrict__ hout,                 // [HDIM] final h (fp32)
              unsigned long long* __restrict__ msg)     // [2][NREP][3][NBLK], zeroed
{
    __shared__ float hsh[HDIM];
    __shared__ float gsum[4][8];
    __shared__ float xgl[32];
    __shared__ float hloc[8];

    const int t  = threadIdx.x;
    const int b  = blockIdx.x;
    const int w  = t >> 6;
    const int L  = t & 63;
    const int rg = L >> 4;
    const int cg = L & 15;
    const int rb = b & (NREP - 1);        // replica this block polls

    float4 wv[2][32];
#pragma unroll
    for (int mp = 0; mp < 2; ++mp) {
        const float* rp = Whh + (size_t)(w * HDIM + 8 * b + 2 * rg + mp) * HDIM + 4 * cg;
#pragma unroll
        for (int j = 0; j < 32; ++j) wv[mp][j] = *(const float4*)(rp + 64 * j);
    }

    float creg = 0.0f;              // cell state (meaningful for t<8 only)
    float hreg[8];
#pragma unroll
    for (int k = 0; k < 8; ++k) hreg[k] = 0.0f;   // h_0 = 0
    float xval = 0.0f;
    if (t < 32)
        xval = __bfloat162float(xg[(size_t)(t >> 3) * HDIM + 8 * b + (t & 7)]);  // s=0

    for (int s = 0; s < SEQ; ++s) {
        // stage h_s (from polled registers) + xg_s (prefetched)
        float4 hv0 = { hreg[0], hreg[1], hreg[2], hreg[3] };
        float4 hv1 = { hreg[4], hreg[5], hreg[6], hreg[7] };
        *(float4*)&hsh[8 * t]     = hv0;
        *(float4*)&hsh[8 * t + 4] = hv1;
        if (t < 32) xgl[t] = xval;
        __syncthreads();                                   // #1

        float a0 = 0.0f, a1 = 0.0f;
#pragma unroll
        for (int j = 0; j < 32; ++j) {
            float4 hv = *(const float4*)&hsh[4 * (cg + 16 * j)];
            a0 += wv[0][j].x * hv.x; a0 += wv[0][j].y * hv.y;
            a0 += wv[0][j].z * hv.z; a0 += wv[0][j].w * hv.w;
            a1 += wv[1][j].x * hv.x; a1 += wv[1][j].y * hv.y;
            a1 += wv[1][j].z * hv.z; a1 += wv[1][j].w * hv.w;
        }
#pragma unroll
        for (int mask = 1; mask <= 8; mask <<= 1) {        // reduce over cg (16 lanes)
            a0 += __shfl_xor(a0, mask, 64);
            a1 += __shfl_xor(a1, mask, 64);
        }
        if (cg == 0) { gsum[w][2 * rg] = a0; gsum[w][2 * rg + 1] = a1; }
        __syncthreads();                                   // #2

        // gates: wave 0 only; hloc handoff to the publishers (t<24) is
        // same-wave, in-order LDS -> no barrier #3 needed.
        if (t < 8) {
            float pi = gsum[0][t] + xgl[t];
            float pf = gsum[1][t] + xgl[8 + t];
            float pg = gsum[2][t] + xgl[16 + t];
            float po = gsum[3][t] + xgl[24 + t];
            float c  = fast_sig(pf) * creg + fast_sig(pi) * fast_tanh(pg);
            creg = c;
            float h  = fast_sig(po) * fast_tanh(c);
            hloc[t] = h;
            if (s == SEQ - 1) hout[8 * b + t] = h;
        }

        if (s + 1 < SEQ) {
            const int p = (s + 1) & 1;
            // publish 3 units x NREP replicas via atomic swap: lane t<24 sends
            // unit j=t%3 of replica r=t/3. One vmem instr in wave 0; 24
            // distinct lines -> parallel MALL banks.
            if (t < 3 * NREP) {
                const int j = t % 3, r = t / 3;
                float v0 = hloc[3 * j], v1 = hloc[3 * j + 1];
                float v2 = (3 * j + 2 < 8) ? hloc[3 * j + 2] : 0.0f;
                unsigned long long u = (unsigned long long)(unsigned short)(s + 1)
                    | ((unsigned long long)f2h(v0) << 16)
                    | ((unsigned long long)f2h(v1) << 32)
                    | ((unsigned long long)f2h(v2) << 48);
                (void)__hip_atomic_exchange(
                        &msg[(size_t)((p * NREP + r) * 3 + j) * NBLK + b], u,
                        __ATOMIC_RELAXED, __HIP_MEMORY_SCOPE_AGENT);
            }
            // prefetch xg for s+1 (latency hidden under the poll)
            if (t < 32)
                xval = __bfloat162float(xg[(size_t)(s + 1) * G4 + (size_t)(t >> 3) * HDIM + 8 * b + (t & 7)]);
            // poll block t's 3 units in THIS block's replica (32 readers/line)
            const unsigned long long* p0 = &msg[(size_t)((p * NREP + rb) * 3 + 0) * NBLK + t];
            const unsigned long long* p1 = &msg[(size_t)((p * NREP + rb) * 3 + 1) * NBLK + t];
            const unsigned long long* p2 = &msg[(size_t)((p * NREP + rb) * 3 + 2) * NBLK + t];
            const unsigned tgt = (unsigned)(s + 1);
            unsigned long long v0, v1, v2;
            do {
                v0 = __hip_atomic_load(p0, __ATOMIC_RELAXED, __HIP_MEMORY_SCOPE_AGENT);
                v1 = __hip_atomic_load(p1, __ATOMIC_RELAXED, __HIP_MEMORY_SCOPE_AGENT);
                v2 = __hip_atomic_load(p2, __ATOMIC_RELAXED, __HIP_MEMORY_SCOPE_AGENT);
            } while ((unsigned)(v0 & 0xFFFFu) < tgt ||
                     (unsigned)(v1 & 0xFFFFu) < tgt ||
                     (unsigned)(v2 & 0xFFFFu) < tgt);
            hreg[0] = h2f((unsigned short)(v0 >> 16));
            hreg[1] = h2f((unsigned short)(v0 >> 32));
            hreg[2] = h2f((unsigned short)(v0 >> 48));
            hreg[3] = h2f((unsigned short)(v1 >> 16));
            hreg[4] = h2f((unsigned short)(v1 >> 32));
            hreg[5] = h2f((unsigned short)(v1 >> 48));
            hreg[6] = h2f((unsigned short)(v2 >> 16));
            hreg[7] = h2f((unsigned short)(v2 >> 32));
        }
    }
}

// ---------------- phase 3: out[o] = h . Wfc[o,:] + bfc[o] ----------------------
__global__ __launch_bounds__(64)
void fc_kernel(const float* __restrict__ h, const float* __restrict__ Wfc,
               const float* __restrict__ bfc, float* __restrict__ out)
{
    const int o = blockIdx.x;
    const int L = threadIdx.x;
    const float* wr = Wfc + (size_t)o * HDIM;
    float s = 0.0f;
#pragma unroll
    for (int jj = 0; jj < 8; ++jj) {
        float4 wvv = *(const float4*)(wr + 4 * (L + 64 * jj));
        float4 hv  = *(const float4*)(h  + 4 * (L + 64 * jj));
        s += wvv.x * hv.x + wvv.y * hv.y + wvv.z * hv.z + wvv.w * hv.w;
    }
#pragma unroll
    for (int mask = 1; mask <= 32; mask <<= 1) s += __shfl_xor(s, mask, 64);
    if (L == 0) out[o] = s + bfc[o];
}

// ---------------- launcher -----------------------------------------------------
extern "C" void kernel_launch(void* const* d_in, const int* in_sizes, int n_in,
                              void* d_out, int out_size, void* d_ws, size_t ws_size,
                              hipStream_t stream)
{
    (void)in_sizes; (void)n_in; (void)out_size; (void)ws_size;
    const float* x   = (const float*)d_in[0];
    const float* Wih = (const float*)d_in[1];
    const float* Whh = (const float*)d_in[2];
    const float* bih = (const float*)d_in[3];
    const float* bhh = (const float*)d_in[4];
    const float* Wfc = (const float*)d_in[5];
    const float* bfc = (const float*)d_in[6];
    float* out = (float*)d_out;

    // ws layout: xg bf16 [SEQ][G4] (64 MiB) | hout fp32 [HDIM] | msg u64 [2][NREP][3][NBLK]
    __hip_bfloat16* xg       = (__hip_bfloat16*)d_ws;
    float* hout              = (float*)((char*)d_ws + (size_t)SEQ * G4 * sizeof(__hip_bfloat16));
    unsigned long long* msg  = (unsigned long long*)(hout + HDIM);

    // ws is poisoned 0xAA before every launch -> tags would read as fresh; MUST zero.
    (void)hipMemsetAsync(msg, 0, (size_t)2 * NREP * 3 * NBLK * sizeof(unsigned long long), stream);

    dim3 g1(G4 / BN, SEQ / BM);  // (64, 32)
    hipLaunchKernelGGL(xg_gemm, g1, dim3(256), 0, stream, x, Wih, bih, bhh, xg);

    // lstm_rec needs all 256 blocks co-resident. Prefer the cooperative-launch
    // guarantee; if the API refuses, fall back to a plain launch: grid==256
    // with 1 block/CU on an idle 256-CU device is co-resident by construction.
    float* hout_arg = hout;
    unsigned long long* msg_arg = msg;
    void* args[] = { (void*)&Whh, (void*)&xg, (void*)&hout_arg, (void*)&msg_arg };
    hipError_t ce = hipLaunchCooperativeKernel((const void*)lstm_rec, dim3(NBLK), dim3(256),
                                               args, 0, stream);
    if (ce != hipSuccess) {
        hipLaunchKernelGGL(lstm_rec, dim3(NBLK), dim3(256), 0, stream, Whh, xg, hout, msg);
    }

    hipLaunchKernelGGL(fc_kernel, dim3(2048), dim3(64), 0, stream, hout, Wfc, bfc, out);
}